// Round 6
// baseline (930.696 us; speedup 1.0000x reference)
//
#include <hip/hip_runtime.h>

#define NN 30000
#define NE 120000
#define NG 938   // ceil(NN/32)
#define TPB 256

__device__ __forceinline__ float blo(unsigned u) { return __uint_as_float(u << 16); }
__device__ __forceinline__ float bhi(unsigned u) { return __uint_as_float(u & 0xffff0000u); }

__global__ void k_zero(int* __restrict__ cnt) {
  int n = blockIdx.x * TPB + threadIdx.x;
  if (n < NN) cnt[n] = 0;
}

// kc[e*8+k] = relu(ea@k_w1+k_b1); cnt[dst]++
__global__ void k_prep(const float* __restrict__ ea, const float* __restrict__ w1,
                       const float* __restrict__ b1, const int* __restrict__ dst,
                       float* __restrict__ kc, int* __restrict__ cnt) {
  int e = blockIdx.x * TPB + threadIdx.x;
  if (e >= NE) return;
  float a[6];
#pragma unroll
  for (int i = 0; i < 6; i++) a[i] = ea[e * 6 + i];
#pragma unroll
  for (int k = 0; k < 8; k++) {
    float s = b1[k];
#pragma unroll
    for (int i = 0; i < 6; i++) s = fmaf(a[i], w1[i * 8 + k], s);
    kc[e * 8 + k] = fmaxf(s, 0.f);
  }
  atomicAdd(&cnt[dst[e]], 1);
}

// single-block prefix scan: rowstart/wpos = exclusive prefix of cnt; icnt = 1/max(cnt,1)
__global__ void k_scan(const int* __restrict__ cnt, int* __restrict__ rowstart,
                       int* __restrict__ wpos, float* __restrict__ icnt) {
  __shared__ int S[1024];
  int t = threadIdx.x;
  int base = t * 30;
  int s = 0;
  for (int j = 0; j < 30; j++) {
    int n = base + j;
    if (n < NN) s += cnt[n];
  }
  S[t] = s;
  __syncthreads();
  for (int off = 1; off < 1024; off <<= 1) {
    int v = S[t] + ((t >= off) ? S[t - off] : 0);
    __syncthreads();
    S[t] = v;
    __syncthreads();
  }
  int pref = (t > 0) ? S[t - 1] : 0;
  for (int j = 0; j < 30; j++) {
    int n = base + j;
    if (n < NN) {
      int c = cnt[n];
      rowstart[n] = pref;
      wpos[n] = pref;
      icnt[n] = 1.f / (float)max(c, 1);
      pref += c;
    }
  }
}

// scatter edge payloads into dst-sorted slots: srcs[pos], kcs[pos*8..]
__global__ void k_scatter(const int* __restrict__ dst, const int* __restrict__ src,
                          const float* __restrict__ kc, int* __restrict__ wpos,
                          int* __restrict__ srcs, float* __restrict__ kcs) {
  int e = blockIdx.x * TPB + threadIdx.x;
  if (e >= NE) return;
  int pos = atomicAdd(&wpos[dst[e]], 1);
  srcs[pos] = src[e];
  float4 a = *(const float4*)&kc[e * 8];
  float4 b = *(const float4*)&kc[e * 8 + 4];
  *(float4*)&kcs[(size_t)pos * 8] = a;
  *(float4*)&kcs[(size_t)pos * 8 + 4] = b;
}

__device__ __forceinline__ unsigned short f2b(float f) {
  unsigned u = __float_as_uint(f);
  return (unsigned short)((u + 0x7fff + ((u >> 16) & 1)) >> 16);  // RNE
}

// CSR aggregate for node n, lane o: acc = sum_edges( Pb1[s] + sum_k ck_k * Pb4[s].k )
__device__ __forceinline__ float aggregate_node(
    int rs, int re, int o, const int* __restrict__ srcs,
    const float* __restrict__ kcs, const uint4* __restrict__ Pb4,
    const unsigned* __restrict__ Pb1) {
  float acc = 0.f;
  for (int j = rs; j < re; j++) {
    int s = srcs[j];
    float ck = (o < 8) ? kcs[(size_t)j * 8 + o] : 0.f;
    uint4 w = Pb4[(size_t)s * 32 + o];
    unsigned wb = Pb1[(size_t)s * 32 + o];
    acc += blo(wb);  // bias row, coefficient 1
    acc = fmaf(__shfl(ck, 0, 32), blo(w.x), acc);
    acc = fmaf(__shfl(ck, 1, 32), bhi(w.x), acc);
    acc = fmaf(__shfl(ck, 2, 32), blo(w.y), acc);
    acc = fmaf(__shfl(ck, 3, 32), bhi(w.y), acc);
    acc = fmaf(__shfl(ck, 4, 32), blo(w.z), acc);
    acc = fmaf(__shfl(ck, 5, 32), bhi(w.z), acc);
    acc = fmaf(__shfl(ck, 6, 32), blo(w.w), acc);
    acc = fmaf(__shfl(ck, 7, 32), bhi(w.w), acc);
  }
  return acc;
}

// 32-node transform: Pb4 (k0..7 bf16 pairs), Pb1 (k8), Pr (root term, f32)
__device__ __forceinline__ void transform32(const float* hL, const float* Wl,
                                            uint4* __restrict__ Pb4,
                                            unsigned* __restrict__ Pb1,
                                            float* __restrict__ Pr,
                                            int base, int tid) {
  int g = tid >> 5, o = tid & 31, sw = (o & 7) << 2;
#pragma unroll
  for (int pp = 0; pp < 2; pp++) {
    int ln0 = pp * 16 + g, ln1 = ln0 + 8;
    float4 hv0[8], hv1[8];
#pragma unroll
    for (int c = 0; c < 8; c++) {
      hv0[c] = *(const float4*)&hL[ln0 * 32 + c * 4];
      hv1[c] = *(const float4*)&hL[ln1 * 32 + c * 4];
    }
    int n0 = base + ln0, n1 = base + ln1;
    float a0[10], a1[10];
#pragma unroll
    for (int k = 0; k < 10; k++) {
      float x0 = 0.f, x1 = 0.f;
#pragma unroll
      for (int c = 0; c < 8; c++) {
        float4 w = *(const float4*)&Wl[k * 1024 + o * 32 + ((c << 2) ^ sw)];
        x0 = fmaf(hv0[c].x, w.x, x0); x1 = fmaf(hv1[c].x, w.x, x1);
        x0 = fmaf(hv0[c].y, w.y, x0); x1 = fmaf(hv1[c].y, w.y, x1);
        x0 = fmaf(hv0[c].z, w.z, x0); x1 = fmaf(hv1[c].z, w.z, x1);
        x0 = fmaf(hv0[c].w, w.w, x0); x1 = fmaf(hv1[c].w, w.w, x1);
      }
      a0[k] = x0; a1[k] = x1;
    }
    if (n0 < NN) {
      uint4 q;
      q.x = f2b(a0[0]) | ((unsigned)f2b(a0[1]) << 16);
      q.y = f2b(a0[2]) | ((unsigned)f2b(a0[3]) << 16);
      q.z = f2b(a0[4]) | ((unsigned)f2b(a0[5]) << 16);
      q.w = f2b(a0[6]) | ((unsigned)f2b(a0[7]) << 16);
      Pb4[(size_t)n0 * 32 + o] = q;
      Pb1[(size_t)n0 * 32 + o] = f2b(a0[8]);
      Pr[(size_t)n0 * 32 + o] = a0[9];
    }
    if (n1 < NN) {
      uint4 q;
      q.x = f2b(a1[0]) | ((unsigned)f2b(a1[1]) << 16);
      q.y = f2b(a1[2]) | ((unsigned)f2b(a1[3]) << 16);
      q.z = f2b(a1[4]) | ((unsigned)f2b(a1[5]) << 16);
      q.w = f2b(a1[6]) | ((unsigned)f2b(a1[7]) << 16);
      Pb4[(size_t)n1 * 32 + o] = q;
      Pb1[(size_t)n1 * 32 + o] = f2b(a1[8]);
      Pr[(size_t)n1 * 32 + o] = a1[9];
    }
  }
}

// MODE 0: h0 = fc1(x) -> transform.  MODE 1: CSR-aggregate -> h -> transform.
template <int MODE>
__global__ __launch_bounds__(TPB, 2) void k_layer(
    const float* __restrict__ x, const float* __restrict__ fc1w,
    const float* __restrict__ fc1b, const float* __restrict__ kw2,
    const float* __restrict__ kb2, const float* __restrict__ root,
    const float* __restrict__ cbias, const int* __restrict__ rowstart,
    const int* __restrict__ cnt, const float* __restrict__ icnt,
    const int* __restrict__ srcs, const float* __restrict__ kcs,
    const uint4* __restrict__ Pb4i, const unsigned* __restrict__ Pb1i,
    const float* __restrict__ Pri, uint4* __restrict__ Pb4o,
    unsigned* __restrict__ Pb1o, float* __restrict__ Pro) {
  __shared__ float Wl[10 * 1024];
  __shared__ float hL[1024];
  int tid = threadIdx.x;
  int base = blockIdx.x * 32;
  for (int f = tid; f < 10 * 1024; f += TPB) {
    int k = f >> 10, rem = f & 1023, i = rem >> 5, o = rem & 31;
    float v;
    if (f < 8192) v = kw2[f];
    else if (f < 9216) v = kb2[f - 8192];
    else v = root[f - 9216];
    Wl[(k * 1024 + o * 32 + i) ^ ((o & 7) << 2)] = v;
  }
  int g = tid >> 5, o = tid & 31;
  if (MODE == 0) {
    for (int e2 = tid; e2 < 1024; e2 += TPB) {
      int ln = e2 >> 5, oo = e2 & 31, n = base + ln;
      hL[e2] = (n < NN) ? fmaf(x[n], fc1w[oo], fc1b[oo]) : 0.f;
    }
  } else {
#pragma unroll
    for (int q = 0; q < 4; q++) {
      int ln = q * 8 + g;
      int n = base + ln;
      int rs = 0, re = 0;
      if (n < NN) { rs = rowstart[n]; re = rs + cnt[n]; }
      float acc = aggregate_node(rs, re, o, srcs, kcs, Pb4i, Pb1i);
      float h = 0.f;
      if (n < NN)
        h = fmaxf(fmaf(acc, icnt[n], Pri[(size_t)n * 32 + o] + cbias[o]), 0.f);
      hL[ln * 32 + o] = h;
    }
  }
  __syncthreads();
  transform32(hL, Wl, Pb4o, Pb1o, Pro, base, tid);
}

// final layer: aggregate -> h -> out = h @ fc2w + fc2b  (no LDS, high occupancy)
__global__ void k_final(const int* __restrict__ rowstart, const int* __restrict__ cnt,
                        const float* __restrict__ icnt, const int* __restrict__ srcs,
                        const float* __restrict__ kcs, const uint4* __restrict__ Pb4,
                        const unsigned* __restrict__ Pb1, const float* __restrict__ Pr,
                        const float* __restrict__ cbias, const float* __restrict__ fc2w,
                        const float* __restrict__ fc2b, float* __restrict__ out) {
  int t = blockIdx.x * TPB + threadIdx.x;
  int n = t >> 5, o = t & 31;
  if (n >= NN) return;
  int rs = rowstart[n], re = rs + cnt[n];
  float acc = aggregate_node(rs, re, o, srcs, kcs, Pb4, Pb1);
  float h = fmaxf(fmaf(acc, icnt[n], Pr[(size_t)n * 32 + o] + cbias[o]), 0.f);
  float s = h * fc2w[o];
#pragma unroll
  for (int d = 16; d; d >>= 1) s += __shfl_xor(s, d, 32);
  if (o == 0) out[n] = s + fc2b[0];
}

extern "C" void kernel_launch(void* const* d_in, const int* in_sizes, int n_in,
                              void* d_out, int out_size, void* d_ws, size_t ws_size,
                              hipStream_t stream) {
  const float* x     = (const float*)d_in[0];
  const int*   ei    = (const int*)d_in[1];
  const float* ea    = (const float*)d_in[2];
  const float* fc1w  = (const float*)d_in[3];
  const float* fc1b  = (const float*)d_in[4];
  const float* kw1   = (const float*)d_in[5];
  const float* kb1   = (const float*)d_in[6];
  const float* kw2   = (const float*)d_in[7];
  const float* kb2   = (const float*)d_in[8];
  const float* root  = (const float*)d_in[9];
  const float* cbias = (const float*)d_in[10];
  const float* fc2w  = (const float*)d_in[11];
  const float* fc2b  = (const float*)d_in[12];
  float* out = (float*)d_out;
  const int* srcp = ei;
  const int* dstp = ei + NE;

  float* ws = (float*)d_ws;
  float* kc       = ws;                        // NE*8
  float* kcs      = kc + NE * 8;               // NE*8
  int*   srcs     = (int*)(kcs + NE * 8);      // NE
  float* icnt     = (float*)(srcs + NE);       // NN
  float* Pr0      = icnt + NN;                 // NN*32
  float* Pr1      = Pr0 + NN * 32;             // NN*32
  int*   cnt      = (int*)(Pr1 + NN * 32);     // NN
  int*   rowstart = cnt + NN;                  // NN
  int*   wpos     = rowstart + NN;             // NN
  uint4* Pb4_0    = (uint4*)(wpos + NN);       // NN*32 uint4
  uint4* Pb4_1    = Pb4_0 + (size_t)NN * 32;   // NN*32 uint4
  unsigned* Pb1_0 = (unsigned*)(Pb4_1 + (size_t)NN * 32);  // NN*32
  unsigned* Pb1_1 = Pb1_0 + (size_t)NN * 32;                // NN*32

  k_zero<<<(NN + TPB - 1) / TPB, TPB, 0, stream>>>(cnt);
  k_prep<<<(NE + TPB - 1) / TPB, TPB, 0, stream>>>(ea, kw1, kb1, dstp, kc, cnt);
  k_scan<<<1, 1024, 0, stream>>>(cnt, rowstart, wpos, icnt);
  k_scatter<<<(NE + TPB - 1) / TPB, TPB, 0, stream>>>(dstp, srcp, kc, wpos, srcs, kcs);

  k_layer<0><<<NG, TPB, 0, stream>>>(x, fc1w, fc1b, kw2, kb2, root, cbias,
                                     rowstart, cnt, icnt, srcs, kcs,
                                     Pb4_0, Pb1_0, Pr0, Pb4_0, Pb1_0, Pr0);
  k_layer<1><<<NG, TPB, 0, stream>>>(x, fc1w, fc1b, kw2, kb2, root, cbias,
                                     rowstart, cnt, icnt, srcs, kcs,
                                     Pb4_0, Pb1_0, Pr0, Pb4_1, Pb1_1, Pr1);
  k_layer<1><<<NG, TPB, 0, stream>>>(x, fc1w, fc1b, kw2, kb2, root, cbias,
                                     rowstart, cnt, icnt, srcs, kcs,
                                     Pb4_1, Pb1_1, Pr1, Pb4_0, Pb1_0, Pr0);
  k_layer<1><<<NG, TPB, 0, stream>>>(x, fc1w, fc1b, kw2, kb2, root, cbias,
                                     rowstart, cnt, icnt, srcs, kcs,
                                     Pb4_0, Pb1_0, Pr0, Pb4_1, Pb1_1, Pr1);
  k_final<<<(NN * 32 + TPB - 1) / TPB, TPB, 0, stream>>>(
      rowstart, cnt, icnt, srcs, kcs, Pb4_1, Pb1_1, Pr1, cbias, fc2w, fc2b, out);
}